// Round 1
// baseline (338.026 us; speedup 1.0000x reference)
//
#include <hip/hip_runtime.h>

// Problem constants (from reference): x is (B=32, NC=64, H=128, W=128) fp32.
// out[b,j,hw] = exp( sum_i log(relu(x[b,i,hw])+0.1) * E[i,j] ) + bias[j]
#define NCH 64
#define HWSZ 16384   // 128*128
#define NPOINTS (32 * HWSZ)  // B * H * W = 524288

__global__ __launch_bounds__(256) void fused_log_einsum_exp(
    const float* __restrict__ x,
    const float* __restrict__ E,     // (64,64) row-major: E[i*64+j]
    const float* __restrict__ bias,  // (64)
    float* __restrict__ out)
{
    __shared__ float Es[NCH * NCH];   // 16 KiB
    __shared__ float bs[NCH];

    // Cooperative load of E: 4096 floats / 256 threads = 16 each, coalesced.
    #pragma unroll
    for (int k = 0; k < 16; ++k)
        Es[k * 256 + threadIdx.x] = E[k * 256 + threadIdx.x];
    if (threadIdx.x < NCH) bs[threadIdx.x] = bias[threadIdx.x];
    __syncthreads();

    const int p  = blockIdx.x * 256 + threadIdx.x;  // one spatial point/thread
    const int b  = p >> 14;          // p / HWSZ
    const int hw = p & (HWSZ - 1);   // p % HWSZ

    const float* xp = x   + (size_t)b * NCH * HWSZ + hw;
    float*       op = out + (size_t)b * NCH * HWSZ + hw;

    float acc[NCH];
    #pragma unroll
    for (int j = 0; j < NCH; ++j) acc[j] = 0.0f;

    // Stream input channels; each x element is loaded (coalesced) and logged
    // exactly once. E row reads are wave-uniform -> LDS broadcast (ds_read_b128).
    #pragma unroll 4
    for (int i = 0; i < NCH; ++i) {
        float v  = xp[(size_t)i * HWSZ];
        float lx = __logf(fmaxf(v, 0.0f) + 0.1f);
        #pragma unroll
        for (int j = 0; j < NCH; ++j)
            acc[j] = fmaf(lx, Es[i * NCH + j], acc[j]);
    }

    // Epilogue: exp + bias, coalesced stores per output channel.
    #pragma unroll 4
    for (int j = 0; j < NCH; ++j)
        op[(size_t)j * HWSZ] = __expf(acc[j]) + bs[j];
}

extern "C" void kernel_launch(void* const* d_in, const int* in_sizes, int n_in,
                              void* d_out, int out_size, void* d_ws, size_t ws_size,
                              hipStream_t stream) {
    const float* x    = (const float*)d_in[0];
    const float* E    = (const float*)d_in[1];   // (64,64,1,1) -> [i*64+j]
    const float* bias = (const float*)d_in[2];   // (64,1,1)
    float* out = (float*)d_out;

    dim3 grid(NPOINTS / 256), block(256);
    hipLaunchKernelGGL(fused_log_einsum_exp, grid, block, 0, stream,
                       x, E, bias, out);
}